// Round 8
// baseline (340.110 us; speedup 1.0000x reference)
//
#include <hip/hip_runtime.h>

#define NHEADS 12
#define SEQ    1024
#define HDIM   768
#define DHEAD  64
#define BH_TOT 48
#define EPSN   1e-6f

typedef __attribute__((ext_vector_type(8))) short    bf8;  // 8 bf16 (4 VGPRs) MFMA A/B frag
typedef __attribute__((ext_vector_type(4))) short    s4;   // 4 bf16 packed
typedef __attribute__((ext_vector_type(4))) float    fx4;  // MFMA C/D frag / float4
typedef __attribute__((ext_vector_type(4))) _Float16 h4;   // 4 f16 (2 VGPRs) 16x16x16 frag

#define SZT 3145728u   // 48*1024*64 elements (one head-split tensor)
#define WSZ 589824u    // 768*768 elements (one weight matrix)

__device__ __forceinline__ float bf2f(unsigned short h) {
  union { unsigned int u; float f; } v; v.u = ((unsigned int)h) << 16; return v.f;
}
__device__ __forceinline__ unsigned short f2bf(float f) {
  union { float f; unsigned int u; } v; v.f = f;
  unsigned int u = v.u;
  return (unsigned short)((u + 0x7FFFu + ((u >> 16) & 1u)) >> 16);
}

// async global->LDS, 16B per lane; LDS dest = wave-uniform base + lane*16.
typedef __attribute__((address_space(3))) unsigned int lds_u32;
typedef __attribute__((address_space(1))) const unsigned int glb_u32;
__device__ __forceinline__ void gld16(const unsigned short* g, unsigned short* l) {
  __builtin_amdgcn_global_load_lds((glb_u32*)g, (lds_u32*)l, 16, 0, 0);
}

// ---------------------------------------------------------------------------
// One-shot f32 -> bf16 conversion, flat 1D grid (no idle blocks).
// Sources laid out back-to-back: hs,te,se (3*SZT) then Wq..Ws (5*WSZ).
// ---------------------------------------------------------------------------
__global__ void convert_kernel(const float* __restrict__ hs, const float* __restrict__ te,
                               const float* __restrict__ se,
                               const float* __restrict__ Wq, const float* __restrict__ Wk,
                               const float* __restrict__ Wv, const float* __restrict__ Wt,
                               const float* __restrict__ Ws2,
                               unsigned short* __restrict__ ws)
{
  const unsigned int gid = blockIdx.x * 256 + threadIdx.x;   // one per 8 elems
  const unsigned int base = gid * 8;
  const unsigned int NTOT = 3 * SZT + 5 * WSZ;
  if (base >= NTOT) return;
  const float* src;
  unsigned short* dst;
  unsigned int off;
  if (base < 3 * SZT) {
    const unsigned int z = base / SZT;
    off = base - z * SZT;
    src = (z == 0) ? hs : (z == 1) ? te : se;
    dst = ws + (size_t)(5 + z) * SZT;
  } else {
    const unsigned int wb = base - 3 * SZT;
    const unsigned int z = wb / WSZ;
    off = wb - z * WSZ;
    src = (z == 0) ? Wq : (z == 1) ? Wk : (z == 2) ? Wv : (z == 3) ? Wt : Ws2;
    dst = ws + (size_t)8 * SZT + (size_t)z * WSZ;
  }
  const fx4 a = *(const fx4*)(src + off);
  const fx4 b = *(const fx4*)(src + off + 4);
  bf8 o;
#pragma unroll
  for (int j = 0; j < 4; ++j) { o[j] = (short)f2bf(a[j]); o[4 + j] = (short)f2bf(b[j]); }
  *(bf8*)(dst + off) = o;
}

// ---------------------------------------------------------------------------
// Projection GEMM (bf16 in): out = X[4096,768] @ W[768,768]^T + b, head-split.
// Double-buffered gld16 staging, one barrier per K-tile.
// z: 0=Q 1=K 2=V(f16, transposed Vt[bh*64+d][1024]) 3=T 4=S
// ---------------------------------------------------------------------------
__global__ __launch_bounds__(256, 3)
void proj_kernel(unsigned short* __restrict__ ws,
                 const float* __restrict__ bq, const float* __restrict__ bk,
                 const float* __restrict__ bv, const float* __restrict__ bt,
                 const float* __restrict__ bs)
{
  __shared__ unsigned short Xs[2][4096];
  __shared__ unsigned short Ys[2][4096];

  const int z = blockIdx.z;
  const unsigned short* X = ws + (size_t)5 * SZT + (size_t)((z < 3) ? 0 : (z - 2)) * SZT;
  const unsigned short* W = ws + (size_t)8 * SZT + (size_t)z * WSZ;
  const float* bias = (z == 0) ? bq : (z == 1) ? bk : (z == 2) ? bv : (z == 3) ? bt : bs;
  unsigned short* out = ws + (size_t)((z < 2) ? z : (z == 2) ? 4 : (z == 3) ? 2 : 3) * SZT;

  const int tid   = threadIdx.x;
  const int lane  = tid & 63;
  const int wid   = tid >> 6;
  const int wm    = wid >> 1, wn = wid & 1;
  const int colid = lane & 15, quad = lane >> 4;
  const int m0 = blockIdx.y * 128, n0 = blockIdx.x * 128;

  auto stage = [&](int kt, int pb) {
#pragma unroll
    for (int i = 0; i < 2; ++i) {
      const int slot = i * 256 + tid;        // 0..511, 16B each
      const int row = slot >> 2, ch = slot & 3;
      gld16(X + (m0 + row) * HDIM + kt + ch * 8, &Xs[pb][slot * 8]);
      gld16(W + (n0 + row) * HDIM + kt + ch * 8, &Ys[pb][slot * 8]);
    }
  };

  fx4 acc[4][4];
#pragma unroll
  for (int i = 0; i < 4; ++i)
#pragma unroll
    for (int j = 0; j < 4; ++j) acc[i][j] = (fx4){0.f, 0.f, 0.f, 0.f};

  stage(0, 0);
  __syncthreads();

  for (int it = 0; it < 24; ++it) {
    const int pb = it & 1;
    if (it + 1 < 24) stage((it + 1) * 32, pb ^ 1);

    bf8 af[4], bfr[4];
#pragma unroll
    for (int i = 0; i < 4; ++i)
      af[i] = *(const bf8*)&Xs[pb][(wm * 64 + i * 16 + colid) * 32 + quad * 8];
#pragma unroll
    for (int j = 0; j < 4; ++j)
      bfr[j] = *(const bf8*)&Ys[pb][(wn * 64 + j * 16 + colid) * 32 + quad * 8];
#pragma unroll
    for (int i = 0; i < 4; ++i)
#pragma unroll
      for (int j = 0; j < 4; ++j)
        acc[i][j] = __builtin_amdgcn_mfma_f32_16x16x32_bf16(af[i], bfr[j], acc[i][j], 0, 0, 0);
    __syncthreads();
  }

  // Epilogue. C/D layout: col=lane&15, row=quad*4+reg.
  if (z != 2) {
#pragma unroll
    for (int i = 0; i < 4; ++i) {
      const int r0 = m0 + wm * 64 + i * 16 + quad * 4;
      const int bb = r0 >> 10, s0 = r0 & 1023;
#pragma unroll
      for (int j = 0; j < 4; ++j) {
        const int c = n0 + wn * 64 + j * 16 + colid;
        const int h = c >> 6, d = c & 63;
        const float bvl = bias[c];
        unsigned short* op = out + (((bb * NHEADS + h) * SEQ + s0) * DHEAD + d);
#pragma unroll
        for (int reg = 0; reg < 4; ++reg)
          op[reg * DHEAD] = f2bf(acc[i][j][reg] + bvl);
      }
    }
  } else {
#pragma unroll
    for (int i = 0; i < 4; ++i) {
      const int r0 = m0 + wm * 64 + i * 16 + quad * 4;
      const int bb = r0 >> 10, s0 = r0 & 1023;
#pragma unroll
      for (int j = 0; j < 4; ++j) {
        const int c = n0 + wn * 64 + j * 16 + colid;
        const int h = c >> 6, d = c & 63;
        const float bvl = bias[c];
        h4 pk;
#pragma unroll
        for (int reg = 0; reg < 4; ++reg)
          pk[reg] = (_Float16)(acc[i][j][reg] + bvl);
        *(h4*)(void*)(out + ((size_t)((bb * NHEADS + h) * DHEAD + d)) * SEQ + s0) = pk;
      }
    }
  }
}

// ---------------------------------------------------------------------------
// Flash attention pass 1, split-K 2-way on the round-7 structure.
// Wave = 64 q (4 groups of 16) x 512 keys; 1536 waves = 1.5/SIMD (TLP!).
// XCD-swizzled: each XCD owns 6 bh entirely. Spill-free 32-key halves.
// Partials: Opart bf16 @5SZ (2 x SZT), ml float2 @7SZ.
// ---------------------------------------------------------------------------
__global__ __launch_bounds__(64, 2)
void attn1_kernel(const unsigned short* __restrict__ ws,
                  const float* __restrict__ maskb)
{
  const unsigned short* Qb  = ws;
  const unsigned short* GT0 = ws + (size_t)1 * SZT;   // K
  const unsigned short* GT1 = ws + (size_t)2 * SZT;   // T
  const unsigned short* GT2 = ws + (size_t)3 * SZT;   // S
  const _Float16* Vtf = (const _Float16*)(ws + (size_t)4 * SZT);
  unsigned short* Opart = (unsigned short*)ws + (size_t)5 * SZT;
  float2* mlp = (float2*)(ws + (size_t)7 * SZT);

  const int lane  = threadIdx.x & 63;
  const int colid = lane & 15, quad = lane >> 4;

  // XCD swizzle: 1536 blocks; lin&7 = XCD; each XCD owns 6 bh entirely.
  const int lin = blockIdx.x;
  const int xcd = lin & 7;
  const int g2  = lin >> 3;            // 0..191
  const int bh  = xcd * 6 + (g2 % 6);
  const int r   = g2 / 6;              // 0..31
  const int qx  = r & 15;
  const int ks  = r >> 4;              // key split 0/1
  const int b   = bh / NHEADS;
  const int q0  = qx * 64;
  const int base_h = bh * SEQ * DHEAD;

  // Query-side B-frags for 4 q-groups: lane holds B[k=quad*8+j][n=colid].
  bf8 bqf[4][2], btf[4][2], bsf[4][2];
  float rs[4];
#pragma unroll
  for (int g = 0; g < 4; ++g) {
    const int row = q0 + g * 16 + colid;
    const unsigned short* qp = Qb  + base_h + row * 64 + quad * 8;
    const unsigned short* tp = GT1 + base_h + row * 64 + quad * 8;
    const unsigned short* sp = GT2 + base_h + row * 64 + quad * 8;
    bqf[g][0] = *(const bf8*)qp;  bqf[g][1] = *(const bf8*)(qp + 32);
    btf[g][0] = *(const bf8*)tp;  btf[g][1] = *(const bf8*)(tp + 32);
    bsf[g][0] = *(const bf8*)sp;  bsf[g][1] = *(const bf8*)(sp + 32);
    float t2 = 0.f, s2 = 0.f;
#pragma unroll
    for (int fr = 0; fr < 2; ++fr)
#pragma unroll
      for (int j = 0; j < 8; ++j) {
        const float tv = bf2f((unsigned short)btf[g][fr][j]);
        const float sv2 = bf2f((unsigned short)bsf[g][fr][j]);
        t2 += tv * tv; s2 += sv2 * sv2;
      }
    t2 += __shfl_xor(t2, 16); t2 += __shfl_xor(t2, 32);
    s2 += __shfl_xor(s2, 16); s2 += __shfl_xor(s2, 32);
    rs[g] = 1.0f / ((sqrtf(t2) + EPSN) * (sqrtf(s2) + EPSN) * 8.0f);
  }

  float m_[4], l_[4];
  fx4 o[4][4];
#pragma unroll
  for (int g = 0; g < 4; ++g) {
    m_[g] = -1.0e30f; l_[g] = 0.f;
#pragma unroll
    for (int fd = 0; fd < 4; ++fd) o[g][fd] = (fx4){0.f, 0.f, 0.f, 0.f};
  }
  const fx4 zero = (fx4){0.f, 0.f, 0.f, 0.f};

  const int k_lo = ks * 512;
#pragma unroll 1
  for (int kb = k_lo; kb < k_lo + 512; kb += 64) {
#pragma unroll
    for (int hh = 0; hh < 2; ++hh) {
      // ---- 32-key half: load K/T/S frags + V + mask ----
      bf8 ak[2][2], at_[2][2], as_[2][2];
      h4 vv[2][4];
      fx4 mk[2];
#pragma unroll
      for (int ff = 0; ff < 2; ++ff) {
        const int f = hh * 2 + ff;
        const int key = kb + f * 16 + colid;
        const unsigned short* kp  = GT0 + base_h + key * 64 + quad * 8;
        const unsigned short* tp  = GT1 + base_h + key * 64 + quad * 8;
        const unsigned short* spp = GT2 + base_h + key * 64 + quad * 8;
        ak[ff][0]  = *(const bf8*)kp;  ak[ff][1]  = *(const bf8*)(kp + 32);
        at_[ff][0] = *(const bf8*)tp;  at_[ff][1] = *(const bf8*)(tp + 32);
        as_[ff][0] = *(const bf8*)spp; as_[ff][1] = *(const bf8*)(spp + 32);
#pragma unroll
        for (int fd = 0; fd < 4; ++fd)
          vv[ff][fd] = *(const h4*)(Vtf + (size_t)(bh * DHEAD + fd * 16 + colid) * SEQ
                                        + kb + f * 16 + quad * 4);
        mk[ff] = *(const fx4*)(maskb + b * SEQ + kb + f * 16 + quad * 4);
      }

      // ---- per q-group: scores^T, online softmax over 32 keys, PV ----
#pragma unroll
      for (int g = 0; g < 4; ++g) {
        float sv[2][4];
#pragma unroll
        for (int ff = 0; ff < 2; ++ff) {
          fx4 ab = __builtin_amdgcn_mfma_f32_16x16x32_bf16(ak[ff][0], bqf[g][0], zero, 0, 0, 0);
          ab = __builtin_amdgcn_mfma_f32_16x16x32_bf16(ak[ff][1], bqf[g][1], ab, 0, 0, 0);
          fx4 tt = __builtin_amdgcn_mfma_f32_16x16x32_bf16(at_[ff][0], btf[g][0], zero, 0, 0, 0);
          tt = __builtin_amdgcn_mfma_f32_16x16x32_bf16(at_[ff][1], btf[g][1], tt, 0, 0, 0);
          fx4 ss = __builtin_amdgcn_mfma_f32_16x16x32_bf16(as_[ff][0], bsf[g][0], zero, 0, 0, 0);
          ss = __builtin_amdgcn_mfma_f32_16x16x32_bf16(as_[ff][1], bsf[g][1], ss, 0, 0, 0);
#pragma unroll
          for (int reg = 0; reg < 4; ++reg)
            sv[ff][reg] = (ab[reg] * tt[reg]) * ss[reg] * rs[g] + mk[ff][reg];
        }

        float bm = sv[0][0];
#pragma unroll
        for (int ff = 0; ff < 2; ++ff)
#pragma unroll
          for (int reg = 0; reg < 4; ++reg) bm = fmaxf(bm, sv[ff][reg]);
        bm = fmaxf(bm, __shfl_xor(bm, 16));
        bm = fmaxf(bm, __shfl_xor(bm, 32));
        const float mn = fmaxf(m_[g], bm);
        const float alpha = __expf(m_[g] - mn);
        float rsum = 0.f;
        h4 pa[2];
#pragma unroll
        for (int ff = 0; ff < 2; ++ff)
#pragma unroll
          for (int reg = 0; reg < 4; ++reg) {
            const float p = __expf(sv[ff][reg] - mn);
            rsum += p;
            pa[ff][reg] = (_Float16)p;
          }
        rsum += __shfl_xor(rsum, 16);
        rsum += __shfl_xor(rsum, 32);
        l_[g] = l_[g] * alpha + rsum;
        m_[g] = mn;

        float ar[4];
#pragma unroll
        for (int reg = 0; reg < 4; ++reg) ar[reg] = __shfl(alpha, quad * 4 + reg);
#pragma unroll
        for (int fd = 0; fd < 4; ++fd)
#pragma unroll
          for (int reg = 0; reg < 4; ++reg) o[g][fd][reg] *= ar[reg];

#pragma unroll
        for (int ff = 0; ff < 2; ++ff)
#pragma unroll
          for (int fd = 0; fd < 4; ++fd)
            o[g][fd] = __builtin_amdgcn_mfma_f32_16x16x16f16(pa[ff], vv[ff][fd], o[g][fd], 0, 0, 0);
      }
    }
  }

  // Partial store per group: Opart[ks][qr][d] bf16 ; ml (m,l) per q row.
  unsigned short* ob = Opart + (size_t)ks * SZT;
#pragma unroll
  for (int g = 0; g < 4; ++g) {
    const int rowg = bh * SEQ + q0 + g * 16;
#pragma unroll
    for (int reg = 0; reg < 4; ++reg) {
      const int qr = rowg + quad * 4 + reg;
#pragma unroll
      for (int fd = 0; fd < 4; ++fd)
        ob[(size_t)qr * 64 + fd * 16 + colid] = f2bf(o[g][fd][reg]);
    }
    if (quad == 0)
      mlp[(size_t)ks * (BH_TOT * SEQ) + rowg + colid] = make_float2(m_[g], l_[g]);
  }
}

// ---------------------------------------------------------------------------
// Split-K combine: out[b,s,h*64+d] = sum_i w_i O_i / sum_i w_i l_i, w_i=e^{m_i-M}
// ---------------------------------------------------------------------------
__global__ void combine_kernel(const unsigned short* __restrict__ ws,
                               float* __restrict__ outb)
{
  const unsigned short* Opart = ws + (size_t)5 * SZT;
  const float2* mlp = (const float2*)(ws + (size_t)7 * SZT);
  const int gid = blockIdx.x * 256 + threadIdx.x;   // 48*1024*16 threads
  const int row = gid >> 4;                          // bh*1024 + s
  const int dq  = (gid & 15) << 2;
  const float2 ml0 = mlp[row];
  const float2 ml1 = mlp[BH_TOT * SEQ + row];
  const float M = fmaxf(ml0.x, ml1.x);
  const float w0 = __expf(ml0.x - M), w1 = __expf(ml1.x - M);
  const float inv = 1.0f / (w0 * ml0.y + w1 * ml1.y);
  const s4 a0 = *(const s4*)(Opart + (size_t)row * 64 + dq);
  const s4 a1 = *(const s4*)(Opart + (size_t)SZT + (size_t)row * 64 + dq);
  const int bh = row >> 10, s = row & 1023;
  const int bb = bh / NHEADS, h = bh - bb * NHEADS;
  fx4 rr;
#pragma unroll
  for (int j = 0; j < 4; ++j)
    rr[j] = (w0 * bf2f((unsigned short)a0[j]) + w1 * bf2f((unsigned short)a1[j])) * inv;
  *(fx4*)(outb + (size_t)(bb * SEQ + s) * HDIM + h * DHEAD + dq) = rr;
}

extern "C" void kernel_launch(void* const* d_in, const int* in_sizes, int n_in,
                              void* d_out, int out_size, void* d_ws, size_t ws_size,
                              hipStream_t stream)
{
  (void)in_sizes; (void)n_in; (void)out_size; (void)ws_size;
  const float* hs   = (const float*)d_in[0];
  const float* te   = (const float*)d_in[1];
  const float* se   = (const float*)d_in[2];
  const float* mask = (const float*)d_in[3];
  const float* Wq   = (const float*)d_in[4];
  const float* bq   = (const float*)d_in[5];
  const float* Wk   = (const float*)d_in[6];
  const float* bk   = (const float*)d_in[7];
  const float* Wv   = (const float*)d_in[8];
  const float* bv   = (const float*)d_in[9];
  const float* Wt   = (const float*)d_in[10];
  const float* bt   = (const float*)d_in[11];
  const float* Wsp  = (const float*)d_in[12];
  const float* bsp  = (const float*)d_in[13];
  float* out = (float*)d_out;
  unsigned short* ws = (unsigned short*)d_ws;

  // ws layout (ushort units): Qb@0 Kb@1SZ Tb@2SZ Sb@3SZ Vt(f16)@4SZ
  // convert-phase: hsb@5SZ teb@6SZ seb@7SZ W[5]@8SZ+z*WSZ (dead after proj)
  // attn-phase (aliases convert region): Opart@5SZ (2 x SZT), ml(float2)@7SZ
  const unsigned int NTOT = 3 * SZT + 5 * WSZ;
  convert_kernel<<<dim3((NTOT / 8 + 255) / 256), 256, 0, stream>>>(hs, te, se, Wq, Wk, Wv, Wt, Wsp, ws);
  proj_kernel<<<dim3(6, 32, 5), 256, 0, stream>>>(ws, bq, bk, bv, bt, bsp);
  attn1_kernel<<<dim3(1536), 64, 0, stream>>>(ws, mask);
  combine_kernel<<<dim3(BH_TOT * SEQ * 16 / 256), 256, 0, stream>>>(ws, out);
}

// Round 9
// 269.670 us; speedup vs baseline: 1.2612x; 1.2612x over previous
//
#include <hip/hip_runtime.h>

#define NHEADS 12
#define SEQ    1024
#define HDIM   768
#define DHEAD  64
#define BH_TOT 48
#define EPSN   1e-6f

typedef __attribute__((ext_vector_type(8))) short    bf8;  // 8 bf16 (4 VGPRs) MFMA A/B frag
typedef __attribute__((ext_vector_type(4))) float    fx4;  // MFMA C/D frag / float4
typedef __attribute__((ext_vector_type(4))) _Float16 h4;   // 4 f16 (2 VGPRs) 16x16x16 frag

#define SZT 3145728u   // 48*1024*64 elements (one head-split tensor)
#define WSZ 589824u    // 768*768 elements (one weight matrix)

__device__ __forceinline__ float bf2f(unsigned short h) {
  union { unsigned int u; float f; } v; v.u = ((unsigned int)h) << 16; return v.f;
}
__device__ __forceinline__ unsigned short f2bf(float f) {
  union { float f; unsigned int u; } v; v.f = f;
  unsigned int u = v.u;
  return (unsigned short)((u + 0x7FFFu + ((u >> 16) & 1u)) >> 16);
}

// async global->LDS, 16B per lane; LDS dest = wave-uniform base + lane*16.
typedef __attribute__((address_space(3))) unsigned int lds_u32;
typedef __attribute__((address_space(1))) const unsigned int glb_u32;
__device__ __forceinline__ void gld16(const unsigned short* g, unsigned short* l) {
  __builtin_amdgcn_global_load_lds((glb_u32*)g, (lds_u32*)l, 16, 0, 0);
}

// ---------------------------------------------------------------------------
// One-shot f32 -> bf16 conversion, flat 1D grid (no idle blocks).
// ---------------------------------------------------------------------------
__global__ void convert_kernel(const float* __restrict__ hs, const float* __restrict__ te,
                               const float* __restrict__ se,
                               const float* __restrict__ Wq, const float* __restrict__ Wk,
                               const float* __restrict__ Wv, const float* __restrict__ Wt,
                               const float* __restrict__ Ws2,
                               unsigned short* __restrict__ ws)
{
  const unsigned int gid = blockIdx.x * 256 + threadIdx.x;   // one per 8 elems
  const unsigned int base = gid * 8;
  const unsigned int NTOT = 3 * SZT + 5 * WSZ;
  if (base >= NTOT) return;
  const float* src;
  unsigned short* dst;
  unsigned int off;
  if (base < 3 * SZT) {
    const unsigned int z = base / SZT;
    off = base - z * SZT;
    src = (z == 0) ? hs : (z == 1) ? te : se;
    dst = ws + (size_t)(5 + z) * SZT;
  } else {
    const unsigned int wb = base - 3 * SZT;
    const unsigned int z = wb / WSZ;
    off = wb - z * WSZ;
    src = (z == 0) ? Wq : (z == 1) ? Wk : (z == 2) ? Wv : (z == 3) ? Wt : Ws2;
    dst = ws + (size_t)8 * SZT + (size_t)z * WSZ;
  }
  const fx4 a = *(const fx4*)(src + off);
  const fx4 b = *(const fx4*)(src + off + 4);
  bf8 o;
#pragma unroll
  for (int j = 0; j < 4; ++j) { o[j] = (short)f2bf(a[j]); o[4 + j] = (short)f2bf(b[j]); }
  *(bf8*)(dst + off) = o;
}

// ---------------------------------------------------------------------------
// Projection GEMM (bf16 in): out = X[4096,768] @ W[768,768]^T + b, head-split.
// Double-buffered gld16 staging, one barrier per K-tile.
// z: 0=Q 1=K 2=V(f16, transposed Vt[bh*64+d][1024]) 3=T 4=S
// ---------------------------------------------------------------------------
__global__ __launch_bounds__(256, 3)
void proj_kernel(unsigned short* __restrict__ ws,
                 const float* __restrict__ bq, const float* __restrict__ bk,
                 const float* __restrict__ bv, const float* __restrict__ bt,
                 const float* __restrict__ bs)
{
  __shared__ unsigned short Xs[2][4096];
  __shared__ unsigned short Ys[2][4096];

  const int z = blockIdx.z;
  const unsigned short* X = ws + (size_t)5 * SZT + (size_t)((z < 3) ? 0 : (z - 2)) * SZT;
  const unsigned short* W = ws + (size_t)8 * SZT + (size_t)z * WSZ;
  const float* bias = (z == 0) ? bq : (z == 1) ? bk : (z == 2) ? bv : (z == 3) ? bt : bs;
  unsigned short* out = ws + (size_t)((z < 2) ? z : (z == 2) ? 4 : (z == 3) ? 2 : 3) * SZT;

  const int tid   = threadIdx.x;
  const int lane  = tid & 63;
  const int wid   = tid >> 6;
  const int wm    = wid >> 1, wn = wid & 1;
  const int colid = lane & 15, quad = lane >> 4;
  const int m0 = blockIdx.y * 128, n0 = blockIdx.x * 128;

  auto stage = [&](int kt, int pb) {
#pragma unroll
    for (int i = 0; i < 2; ++i) {
      const int slot = i * 256 + tid;        // 0..511, 16B each
      const int row = slot >> 2, ch = slot & 3;
      gld16(X + (m0 + row) * HDIM + kt + ch * 8, &Xs[pb][slot * 8]);
      gld16(W + (n0 + row) * HDIM + kt + ch * 8, &Ys[pb][slot * 8]);
    }
  };

  fx4 acc[4][4];
#pragma unroll
  for (int i = 0; i < 4; ++i)
#pragma unroll
    for (int j = 0; j < 4; ++j) acc[i][j] = (fx4){0.f, 0.f, 0.f, 0.f};

  stage(0, 0);
  __syncthreads();

  for (int it = 0; it < 24; ++it) {
    const int pb = it & 1;
    if (it + 1 < 24) stage((it + 1) * 32, pb ^ 1);

    bf8 af[4], bfr[4];
#pragma unroll
    for (int i = 0; i < 4; ++i)
      af[i] = *(const bf8*)&Xs[pb][(wm * 64 + i * 16 + colid) * 32 + quad * 8];
#pragma unroll
    for (int j = 0; j < 4; ++j)
      bfr[j] = *(const bf8*)&Ys[pb][(wn * 64 + j * 16 + colid) * 32 + quad * 8];
#pragma unroll
    for (int i = 0; i < 4; ++i)
#pragma unroll
      for (int j = 0; j < 4; ++j)
        acc[i][j] = __builtin_amdgcn_mfma_f32_16x16x32_bf16(af[i], bfr[j], acc[i][j], 0, 0, 0);
    __syncthreads();
  }

  // Epilogue. C/D layout: col=lane&15, row=quad*4+reg.
  if (z != 2) {
#pragma unroll
    for (int i = 0; i < 4; ++i) {
      const int r0 = m0 + wm * 64 + i * 16 + quad * 4;
      const int bb = r0 >> 10, s0 = r0 & 1023;
#pragma unroll
      for (int j = 0; j < 4; ++j) {
        const int c = n0 + wn * 64 + j * 16 + colid;
        const int h = c >> 6, d = c & 63;
        const float bvl = bias[c];
        unsigned short* op = out + (((bb * NHEADS + h) * SEQ + s0) * DHEAD + d);
#pragma unroll
        for (int reg = 0; reg < 4; ++reg)
          op[reg * DHEAD] = f2bf(acc[i][j][reg] + bvl);
      }
    }
  } else {
#pragma unroll
    for (int i = 0; i < 4; ++i) {
      const int r0 = m0 + wm * 64 + i * 16 + quad * 4;
      const int bb = r0 >> 10, s0 = r0 & 1023;
#pragma unroll
      for (int j = 0; j < 4; ++j) {
        const int c = n0 + wn * 64 + j * 16 + colid;
        const int h = c >> 6, d = c & 63;
        const float bvl = bias[c];
        h4 pk;
#pragma unroll
        for (int reg = 0; reg < 4; ++reg)
          pk[reg] = (_Float16)(acc[i][j][reg] + bvl);
        *(h4*)(void*)(out + ((size_t)((bb * NHEADS + h) * DHEAD + d)) * SEQ + s0) = pk;
      }
    }
  }
}

// ---------------------------------------------------------------------------
// Flash attention: wave = 32 q (2 groups of 16), full 1024 keys, 64-thread
// blocks, grid 1536 => 1.5 waves/SIMD REAL occupancy (working set ~210 regs
// fits the 256-reg budget of 2 waves/SIMD -- round 8's cap-induced spill
// storm is structurally avoided). XCD-swizzled: each XCD owns 6 bh.
// Spill-safe 32-key halves; transposed scores => per-lane softmax (2 shfl);
// P regs feed f16 PV directly. No split-K, no partials.
// ---------------------------------------------------------------------------
__global__ __launch_bounds__(64, 2)
void attn_kernel(const unsigned short* __restrict__ ws,
                 const float* __restrict__ maskb,
                 float* __restrict__ outb)
{
  const unsigned short* Qb  = ws;
  const unsigned short* GT0 = ws + (size_t)1 * SZT;   // K
  const unsigned short* GT1 = ws + (size_t)2 * SZT;   // T
  const unsigned short* GT2 = ws + (size_t)3 * SZT;   // S
  const _Float16* Vtf = (const _Float16*)(ws + (size_t)4 * SZT);

  const int lane  = threadIdx.x & 63;
  const int colid = lane & 15, quad = lane >> 4;

  // XCD swizzle: 1536 blocks; lin&7 = XCD; each XCD owns 6 bh entirely.
  const int lin = blockIdx.x;
  const int xcd = lin & 7;
  const int g2  = lin >> 3;            // 0..191
  const int bh  = xcd * 6 + (g2 % 6);
  const int qx  = g2 / 6;              // 0..31
  const int b   = bh / NHEADS, h = bh % NHEADS;
  const int q0  = qx * 32;
  const int base_h = bh * SEQ * DHEAD;

  // Query-side B-frags for 2 q-groups: lane holds B[k=quad*8+j][n=colid].
  bf8 bqf[2][2], btf[2][2], bsf[2][2];
  float rs[2];
#pragma unroll
  for (int g = 0; g < 2; ++g) {
    const int row = q0 + g * 16 + colid;
    const unsigned short* qp = Qb  + base_h + row * 64 + quad * 8;
    const unsigned short* tp = GT1 + base_h + row * 64 + quad * 8;
    const unsigned short* sp = GT2 + base_h + row * 64 + quad * 8;
    bqf[g][0] = *(const bf8*)qp;  bqf[g][1] = *(const bf8*)(qp + 32);
    btf[g][0] = *(const bf8*)tp;  btf[g][1] = *(const bf8*)(tp + 32);
    bsf[g][0] = *(const bf8*)sp;  bsf[g][1] = *(const bf8*)(sp + 32);
    float t2 = 0.f, s2 = 0.f;
#pragma unroll
    for (int fr = 0; fr < 2; ++fr)
#pragma unroll
      for (int j = 0; j < 8; ++j) {
        const float tv = bf2f((unsigned short)btf[g][fr][j]);
        const float sv2 = bf2f((unsigned short)bsf[g][fr][j]);
        t2 += tv * tv; s2 += sv2 * sv2;
      }
    t2 += __shfl_xor(t2, 16); t2 += __shfl_xor(t2, 32);
    s2 += __shfl_xor(s2, 16); s2 += __shfl_xor(s2, 32);
    rs[g] = 1.0f / ((sqrtf(t2) + EPSN) * (sqrtf(s2) + EPSN) * 8.0f);
  }

  float m_[2], l_[2];
  fx4 o[2][4];
#pragma unroll
  for (int g = 0; g < 2; ++g) {
    m_[g] = -1.0e30f; l_[g] = 0.f;
#pragma unroll
    for (int fd = 0; fd < 4; ++fd) o[g][fd] = (fx4){0.f, 0.f, 0.f, 0.f};
  }
  const fx4 zero = (fx4){0.f, 0.f, 0.f, 0.f};

#pragma unroll 1
  for (int kb = 0; kb < SEQ; kb += 64) {
#pragma unroll
    for (int hh = 0; hh < 2; ++hh) {
      // ---- 32-key half: load K/T/S frags + V + mask ----
      bf8 ak[2][2], at_[2][2], as_[2][2];
      h4 vv[2][4];
      fx4 mk[2];
#pragma unroll
      for (int ff = 0; ff < 2; ++ff) {
        const int f = hh * 2 + ff;
        const int key = kb + f * 16 + colid;
        const unsigned short* kp  = GT0 + base_h + key * 64 + quad * 8;
        const unsigned short* tp  = GT1 + base_h + key * 64 + quad * 8;
        const unsigned short* spp = GT2 + base_h + key * 64 + quad * 8;
        ak[ff][0]  = *(const bf8*)kp;  ak[ff][1]  = *(const bf8*)(kp + 32);
        at_[ff][0] = *(const bf8*)tp;  at_[ff][1] = *(const bf8*)(tp + 32);
        as_[ff][0] = *(const bf8*)spp; as_[ff][1] = *(const bf8*)(spp + 32);
#pragma unroll
        for (int fd = 0; fd < 4; ++fd)
          vv[ff][fd] = *(const h4*)(Vtf + (size_t)(bh * DHEAD + fd * 16 + colid) * SEQ
                                        + kb + f * 16 + quad * 4);
        mk[ff] = *(const fx4*)(maskb + b * SEQ + kb + f * 16 + quad * 4);
      }

      // ---- per q-group: scores^T, online softmax over 32 keys, PV ----
#pragma unroll
      for (int g = 0; g < 2; ++g) {
        float sv[2][4];
#pragma unroll
        for (int ff = 0; ff < 2; ++ff) {
          fx4 ab = __builtin_amdgcn_mfma_f32_16x16x32_bf16(ak[ff][0], bqf[g][0], zero, 0, 0, 0);
          ab = __builtin_amdgcn_mfma_f32_16x16x32_bf16(ak[ff][1], bqf[g][1], ab, 0, 0, 0);
          fx4 tt = __builtin_amdgcn_mfma_f32_16x16x32_bf16(at_[ff][0], btf[g][0], zero, 0, 0, 0);
          tt = __builtin_amdgcn_mfma_f32_16x16x32_bf16(at_[ff][1], btf[g][1], tt, 0, 0, 0);
          fx4 ss = __builtin_amdgcn_mfma_f32_16x16x32_bf16(as_[ff][0], bsf[g][0], zero, 0, 0, 0);
          ss = __builtin_amdgcn_mfma_f32_16x16x32_bf16(as_[ff][1], bsf[g][1], ss, 0, 0, 0);
#pragma unroll
          for (int reg = 0; reg < 4; ++reg)
            sv[ff][reg] = (ab[reg] * tt[reg]) * ss[reg] * rs[g] + mk[ff][reg];
        }

        float bm = sv[0][0];
#pragma unroll
        for (int ff = 0; ff < 2; ++ff)
#pragma unroll
          for (int reg = 0; reg < 4; ++reg) bm = fmaxf(bm, sv[ff][reg]);
        bm = fmaxf(bm, __shfl_xor(bm, 16));
        bm = fmaxf(bm, __shfl_xor(bm, 32));
        const float mn = fmaxf(m_[g], bm);
        const float alpha = __expf(m_[g] - mn);
        float rsum = 0.f;
        h4 pa[2];
#pragma unroll
        for (int ff = 0; ff < 2; ++ff)
#pragma unroll
          for (int reg = 0; reg < 4; ++reg) {
            const float p = __expf(sv[ff][reg] - mn);
            rsum += p;
            pa[ff][reg] = (_Float16)p;
          }
        rsum += __shfl_xor(rsum, 16);
        rsum += __shfl_xor(rsum, 32);
        l_[g] = l_[g] * alpha + rsum;
        m_[g] = mn;

        float ar[4];
#pragma unroll
        for (int reg = 0; reg < 4; ++reg) ar[reg] = __shfl(alpha, quad * 4 + reg);
#pragma unroll
        for (int fd = 0; fd < 4; ++fd)
#pragma unroll
          for (int reg = 0; reg < 4; ++reg) o[g][fd][reg] *= ar[reg];

#pragma unroll
        for (int ff = 0; ff < 2; ++ff)
#pragma unroll
          for (int fd = 0; fd < 4; ++fd)
            o[g][fd] = __builtin_amdgcn_mfma_f32_16x16x16f16(pa[ff], vv[ff][fd], o[g][fd], 0, 0, 0);
      }
    }
  }

  // Epilogue per group: out[b, s, h*64+d] = O / l  (f32 out).
#pragma unroll
  for (int g = 0; g < 2; ++g) {
    const float linv = 1.0f / l_[g];
    float ir[4];
#pragma unroll
    for (int reg = 0; reg < 4; ++reg) ir[reg] = __shfl(linv, quad * 4 + reg);
#pragma unroll
    for (int reg = 0; reg < 4; ++reg) {
      const int s = q0 + g * 16 + quad * 4 + reg;
#pragma unroll
      for (int fd = 0; fd < 4; ++fd)
        outb[(size_t)(b * SEQ + s) * HDIM + h * DHEAD + fd * 16 + colid] = o[g][fd][reg] * ir[reg];
    }
  }
}

extern "C" void kernel_launch(void* const* d_in, const int* in_sizes, int n_in,
                              void* d_out, int out_size, void* d_ws, size_t ws_size,
                              hipStream_t stream)
{
  (void)in_sizes; (void)n_in; (void)out_size; (void)ws_size;
  const float* hs   = (const float*)d_in[0];
  const float* te   = (const float*)d_in[1];
  const float* se   = (const float*)d_in[2];
  const float* mask = (const float*)d_in[3];
  const float* Wq   = (const float*)d_in[4];
  const float* bq   = (const float*)d_in[5];
  const float* Wk   = (const float*)d_in[6];
  const float* bk   = (const float*)d_in[7];
  const float* Wv   = (const float*)d_in[8];
  const float* bv   = (const float*)d_in[9];
  const float* Wt   = (const float*)d_in[10];
  const float* bt   = (const float*)d_in[11];
  const float* Wsp  = (const float*)d_in[12];
  const float* bsp  = (const float*)d_in[13];
  float* out = (float*)d_out;
  unsigned short* ws = (unsigned short*)d_ws;

  // ws layout (ushort units): Qb@0 Kb@1SZ Tb@2SZ Sb@3SZ Vt(f16)@4SZ
  // convert-phase: hsb@5SZ teb@6SZ seb@7SZ W[5]@8SZ+z*WSZ (dead after proj)
  const unsigned int NTOT = 3 * SZT + 5 * WSZ;
  convert_kernel<<<dim3((NTOT / 8 + 255) / 256), 256, 0, stream>>>(hs, te, se, Wq, Wk, Wv, Wt, Wsp, ws);
  proj_kernel<<<dim3(6, 32, 5), 256, 0, stream>>>(ws, bq, bk, bv, bt, bsp);
  attn_kernel<<<dim3(1536), 64, 0, stream>>>(ws, mask, out);
}